// Round 1
// baseline (939.157 us; speedup 1.0000x reference)
//
#include <hip/hip_runtime.h>

#define N_NODES 100000
#define N_EDGES 1600000
#define CAP 64

typedef unsigned short ushort_t;
typedef __attribute__((ext_vector_type(8))) short bf16x8;
typedef __attribute__((ext_vector_type(4))) float f32x4;

__device__ __forceinline__ unsigned short f2bf(float f) {
  unsigned int u = __float_as_uint(f);
  u = (u + 0x7FFFu + ((u >> 16) & 1u)) >> 16;
  return (unsigned short)u;
}

// ---- degree accumulation: deg[row] += ew ----
__global__ void k_deg(const int* __restrict__ ei, const float* __restrict__ ew,
                      float* __restrict__ deg) {
  int e = blockIdx.x * 256 + threadIdx.x;
  if (e < N_EDGES) atomicAdd(&deg[ei[e]], ew[e]);
}

// ---- deg -> deg^-0.5 in place ----
__global__ void k_dinv(float* deg) {
  int i = blockIdx.x * 256 + threadIdx.x;
  if (i < N_NODES) { float d = deg[i]; deg[i] = d > 0.f ? 1.f / sqrtf(d) : 0.f; }
}

// ---- bucket edges by destination col, storing (row, w) ----
__global__ void k_bucket(const int* __restrict__ ei, const float* __restrict__ ew,
                         const float* __restrict__ dinv, int* __restrict__ cnt,
                         int* __restrict__ bRow, float* __restrict__ bW) {
  int e = blockIdx.x * 256 + threadIdx.x;
  if (e >= N_EDGES) return;
  int r = ei[e], c = ei[N_EDGES + e];
  float wv = -dinv[r] * ew[e] * dinv[c];
  int pos = atomicAdd(&cnt[c], 1);
  if (pos < CAP) { bRow[c * CAP + pos] = r; bW[c * CAP + pos] = wv; }
}

// ---- pack X (cols 0-127) and H (cols 128-255) into bf16 A-matrix U [N][512] ----
__global__ void k_pack_xh(const float* __restrict__ X, const float* __restrict__ H,
                          ushort_t* __restrict__ U) {
  int i = blockIdx.x * 256 + threadIdx.x;
  if (i >= N_NODES * 32) return;
  int n = i >> 5, q = i & 31;
  float4 x = *(const float4*)(X + (size_t)n * 128 + q * 4);
  float4 h = *(const float4*)(H + (size_t)n * 128 + q * 4);
  ushort4 a, bb;
  a.x = f2bf(x.x); a.y = f2bf(x.y); a.z = f2bf(x.z); a.w = f2bf(x.w);
  bb.x = f2bf(h.x); bb.y = f2bf(h.y); bb.z = f2bf(h.z); bb.w = f2bf(h.w);
  *(ushort4*)(U + (size_t)n * 512 + q * 4) = a;
  *(ushort4*)(U + (size_t)n * 512 + 128 + q * 4) = bb;
}

// ---- gather prop: T1 = L_hat @ H; also pack into U cols 256-383 ----
__global__ void k_gather1(const int* __restrict__ cnt, const int* __restrict__ bRow,
                          const float* __restrict__ bW, const float* __restrict__ src,
                          float* __restrict__ T1, ushort_t* __restrict__ U) {
  int node = blockIdx.x * 2 + (threadIdx.x >> 7);
  int d = threadIdx.x & 127;
  if (node >= N_NODES) return;
  int cn = cnt[node]; if (cn > CAP) cn = CAP;
  const int* br = bRow + node * CAP;
  const float* bw = bW + node * CAP;
  float acc = 0.f;
  for (int i = 0; i < cn; ++i)
    acc = fmaf(bw[i], src[(size_t)br[i] * 128 + d], acc);
  T1[(size_t)node * 128 + d] = acc;
  U[(size_t)node * 512 + 256 + d] = f2bf(acc);
}

// ---- gather prop 2: T2 = 2*(L_hat @ T1) - H, packed into U cols 384-511 ----
__global__ void k_gather2(const int* __restrict__ cnt, const int* __restrict__ bRow,
                          const float* __restrict__ bW, const float* __restrict__ T1,
                          const float* __restrict__ H, ushort_t* __restrict__ U) {
  int node = blockIdx.x * 2 + (threadIdx.x >> 7);
  int d = threadIdx.x & 127;
  if (node >= N_NODES) return;
  int cn = cnt[node]; if (cn > CAP) cn = CAP;
  const int* br = bRow + node * CAP;
  const float* bw = bW + node * CAP;
  float acc = 0.f;
  for (int i = 0; i < cn; ++i)
    acc = fmaf(bw[i], T1[(size_t)br[i] * 128 + d], acc);
  float v = 2.f * acc - H[(size_t)node * 128 + d];
  U[(size_t)node * 512 + 384 + d] = f2bf(v);
}

// ---- build B^T [512 j][512 k] bf16, col interleave j = d*4 + g; plus bias[512] ----
__global__ void k_bt(const float* __restrict__ W, const float* __restrict__ b,
                     const float* __restrict__ cW, const float* __restrict__ cb,
                     ushort_t* __restrict__ Bt, float* __restrict__ bias) {
  int idx = blockIdx.x * 256 + threadIdx.x;
  if (idx >= 512 * 512) return;
  int j = idx >> 9, k = idx & 511;
  int dd = j >> 2, g = j & 3;
  float v;
  if (k < 128) v = W[(g * 128 + k) * 128 + dd];
  else {
    int kk = k - 128;
    int blk = kk >> 7;
    v = cW[((g * 3 + blk) * 128 + (kk & 127)) * 128 + dd];
  }
  Bt[idx] = f2bf(v);
  if (k == 0) bias[j] = b[g * 128 + dd] + cb[g * 128 + dd];
}

// ---- fused GEMM (N x 512 x 512, bf16 MFMA) + LSTM epilogue ----
__global__ __launch_bounds__(256) void k_gemm(
    const ushort_t* __restrict__ U, const ushort_t* __restrict__ Bt,
    const float* __restrict__ bias, const float* __restrict__ C,
    float* __restrict__ out) {
  __shared__ float ldsF[8448];           // 33792 B: staging (32KB) then 64x132 f32 tile
  char* ldsA = (char*)ldsF;
  char* ldsB = ldsA + 16384;

  const int tid = threadIdx.x;
  const int lane = tid & 63;
  const int w = tid >> 6;
  const int wr = w >> 1, wc = w & 1;
  const int m0 = blockIdx.y * 128;
  const int n0 = blockIdx.x * 128;
  const int l15 = lane & 15;
  const int l4 = lane >> 4;

  f32x4 acc[4][4] = {};

  for (int kt = 0; kt < 8; ++kt) {
    const int k0 = kt * 64;
#pragma unroll
    for (int is = 0; is < 4; ++is) {
      int s = is * 256 + tid;
      int row = s >> 3;
      int cs = (s & 7) ^ (row & 7);        // inverse-swizzled global source chunk
      const ushort_t* ga = U + (size_t)(m0 + row) * 512 + k0 + cs * 8;
      const ushort_t* gb = Bt + (size_t)(n0 + row) * 512 + k0 + cs * 8;
      char* la = ldsA + (is * 256 + (tid & 192)) * 16;   // wave-uniform base
      char* lb = ldsB + (is * 256 + (tid & 192)) * 16;
      __builtin_amdgcn_global_load_lds((const __attribute__((address_space(1))) void*)ga,
                                       (__attribute__((address_space(3))) void*)la, 16, 0, 0);
      __builtin_amdgcn_global_load_lds((const __attribute__((address_space(1))) void*)gb,
                                       (__attribute__((address_space(3))) void*)lb, 16, 0, 0);
    }
    asm volatile("s_waitcnt vmcnt(0)" ::: "memory");
    __syncthreads();

#pragma unroll
    for (int ks = 0; ks < 2; ++ks) {
      bf16x8 af[4], bfr[4];
#pragma unroll
      for (int mi = 0; mi < 4; ++mi) {
        int ra = wr * 64 + mi * 16 + l15;
        int slot = (ks * 4 + l4) ^ (ra & 7);   // swizzled read
        af[mi] = *(const bf16x8*)(ldsA + ra * 128 + slot * 16);
      }
#pragma unroll
      for (int ni = 0; ni < 4; ++ni) {
        int rb = wc * 64 + ni * 16 + l15;
        int slot = (ks * 4 + l4) ^ (rb & 7);
        bfr[ni] = *(const bf16x8*)(ldsB + rb * 128 + slot * 16);
      }
#pragma unroll
      for (int mi = 0; mi < 4; ++mi)
#pragma unroll
        for (int ni = 0; ni < 4; ++ni)
          acc[mi][ni] = __builtin_amdgcn_mfma_f32_16x16x32_bf16(af[mi], bfr[ni], acc[mi][ni], 0, 0, 0);
    }
    __syncthreads();
  }

  // epilogue: two row-halves through LDS, then fused LSTM elementwise
#pragma unroll
  for (int half = 0; half < 2; ++half) {
    if (wr == half) {
#pragma unroll
      for (int ni = 0; ni < 4; ++ni) {
        int col = wc * 64 + ni * 16 + l15;
        float bv = bias[n0 + col];
#pragma unroll
        for (int mi = 0; mi < 4; ++mi)
#pragma unroll
          for (int r = 0; r < 4; ++r)
            ldsF[(mi * 16 + l4 * 4 + r) * 132 + col] = acc[mi][ni][r] + bv;
      }
    }
    __syncthreads();
    for (int p = tid; p < 64 * 32; p += 256) {
      int rl = p >> 5, f = p & 31;
      int n = m0 + half * 64 + rl;
      if (n < N_NODES) {
        float4 pre = *(const float4*)&ldsF[rl * 132 + f * 4];
        int dg = (n0 >> 2) + f;
        float ig = 1.f / (1.f + __expf(-pre.x));
        float fg = 1.f / (1.f + __expf(-pre.y));
        float zc = fminf(fmaxf(pre.z, -15.f), 15.f);
        float e2 = __expf(2.f * zc);
        float tg = (e2 - 1.f) / (e2 + 1.f);
        float og = 1.f / (1.f + __expf(-pre.w));
        float cOld = C[(size_t)n * 128 + dg];
        float cn = fg * cOld + ig * tg;
        float zn = fminf(fmaxf(cn, -15.f), 15.f);
        float en = __expf(2.f * zn);
        out[(size_t)n * 128 + dg] = og * (en - 1.f) / (en + 1.f);
      }
    }
    __syncthreads();
  }
}

extern "C" void kernel_launch(void* const* d_in, const int* in_sizes, int n_in,
                              void* d_out, int out_size, void* d_ws, size_t ws_size,
                              hipStream_t stream) {
  const float* X  = (const float*)d_in[0];
  const int*   ei = (const int*)d_in[1];
  const float* ew = (const float*)d_in[2];
  const float* H  = (const float*)d_in[3];
  const float* C  = (const float*)d_in[4];
  const float* W  = (const float*)d_in[5];
  const float* b  = (const float*)d_in[6];
  const float* cW = (const float*)d_in[7];
  const float* cb = (const float*)d_in[8];
  float* out = (float*)d_out;
  char* ws = (char*)d_ws;

  float*    deg  = (float*)(ws);                 // 0.4 MB
  int*      cnt  = (int*)(ws + 0x80000);         // 0.4 MB
  int*      bRow = (int*)(ws + 0x100000);        // 25.6 MB
  float*    bW   = (float*)(ws + 0x1B00000);     // 25.6 MB
  float*    T1   = (float*)(ws + 0x3500000);     // 51.2 MB
  ushort_t* U    = (ushort_t*)(ws + 0x6600000);  // (N+128)x512 bf16 = 102.5 MB
  ushort_t* Bt   = (ushort_t*)(ws + 0xC800000);  // 512 KB
  float*    bias = (float*)(ws + 0xC880000);     // 2 KB

  hipMemsetAsync(ws, 0, 0x100000, stream);       // zero deg + cnt

  k_deg<<<(N_EDGES + 255) / 256, 256, 0, stream>>>(ei, ew, deg);
  k_dinv<<<(N_NODES + 255) / 256, 256, 0, stream>>>(deg);
  k_bucket<<<(N_EDGES + 255) / 256, 256, 0, stream>>>(ei, ew, deg, cnt, bRow, bW);
  k_pack_xh<<<(N_NODES * 32 + 255) / 256, 256, 0, stream>>>(X, H, U);
  k_bt<<<1024, 256, 0, stream>>>(W, b, cW, cb, Bt, bias);
  k_gather1<<<N_NODES / 2, 256, 0, stream>>>(cnt, bRow, bW, H, T1, U);
  k_gather2<<<N_NODES / 2, 256, 0, stream>>>(cnt, bRow, bW, T1, H, U);
  dim3 grid(4, 782);
  k_gemm<<<grid, 256, 0, stream>>>(U, Bt, bias, C, out);
}

// Round 2
// 616.328 us; speedup vs baseline: 1.5238x; 1.5238x over previous
//
#include <hip/hip_runtime.h>

#define N_NODES 100000
#define N_EDGES 1600000
#define CAP 64

typedef unsigned short ushort_t;
typedef __attribute__((ext_vector_type(8))) short bf16x8;
typedef __attribute__((ext_vector_type(4))) float f32x4;

__device__ __forceinline__ unsigned short f2bf(float f) {
  unsigned int u = __float_as_uint(f);
  u = (u + 0x7FFFu + ((u >> 16) & 1u)) >> 16;
  return (unsigned short)u;
}

// ---- degree accumulation: deg[row] += ew ----
__global__ void k_deg(const int* __restrict__ ei, const float* __restrict__ ew,
                      float* __restrict__ deg) {
  int e = blockIdx.x * 256 + threadIdx.x;
  if (e < N_EDGES) atomicAdd(&deg[ei[e]], ew[e]);
}

// ---- deg -> deg^-0.5 in place ----
__global__ void k_dinv(float* deg) {
  int i = blockIdx.x * 256 + threadIdx.x;
  if (i < N_NODES) { float d = deg[i]; deg[i] = d > 0.f ? 1.f / sqrtf(d) : 0.f; }
}

// ---- bucket edges by destination col, storing (row, w) ----
__global__ void k_bucket(const int* __restrict__ ei, const float* __restrict__ ew,
                         const float* __restrict__ dinv, int* __restrict__ cnt,
                         int* __restrict__ bRow, float* __restrict__ bW) {
  int e = blockIdx.x * 256 + threadIdx.x;
  if (e >= N_EDGES) return;
  int r = ei[e], c = ei[N_EDGES + e];
  float wv = -dinv[r] * ew[e] * dinv[c];
  int pos = atomicAdd(&cnt[c], 1);
  if (pos < CAP) { bRow[c * CAP + pos] = r; bW[c * CAP + pos] = wv; }
}

// ---- pack X (cols 0-127) and H (cols 128-255) into bf16 A-matrix U [N][512] ----
__global__ void k_pack_xh(const float* __restrict__ X, const float* __restrict__ H,
                          ushort_t* __restrict__ U) {
  int i = blockIdx.x * 256 + threadIdx.x;
  if (i >= N_NODES * 32) return;
  int n = i >> 5, q = i & 31;
  float4 x = *(const float4*)(X + (size_t)n * 128 + q * 4);
  float4 h = *(const float4*)(H + (size_t)n * 128 + q * 4);
  ushort4 a, bb;
  a.x = f2bf(x.x); a.y = f2bf(x.y); a.z = f2bf(x.z); a.w = f2bf(x.w);
  bb.x = f2bf(h.x); bb.y = f2bf(h.y); bb.z = f2bf(h.z); bb.w = f2bf(h.w);
  *(ushort4*)(U + (size_t)n * 512 + q * 4) = a;
  *(ushort4*)(U + (size_t)n * 512 + 128 + q * 4) = bb;
}

// ---- ILP gather: 32 lanes/node (float4 each), 4-deep unroll, 4 accumulators ----
// PHASE 1: T1 = L_hat @ H          -> T1 (f32) + U cols 256..383
// PHASE 2: T2 = 2*(L_hat @ T1) - H -> U cols 384..511
template <int PHASE>
__global__ __launch_bounds__(256) void k_gather(
    const int* __restrict__ cnt, const int* __restrict__ bRow,
    const float* __restrict__ bW, const float* __restrict__ src,
    const float* __restrict__ H, float* __restrict__ T1,
    ushort_t* __restrict__ U) {
  int g = threadIdx.x >> 5, lane = threadIdx.x & 31;
  int node = blockIdx.x * 8 + g;
  if (node >= N_NODES) return;
  int cn = cnt[node]; if (cn > CAP) cn = CAP;
  const int* br = bRow + node * CAP;
  const float* bw = bW + node * CAP;
  const float4* s4 = (const float4*)src;

  float4 a0 = {0.f, 0.f, 0.f, 0.f}, a1 = a0, a2 = a0, a3 = a0;
  int i = 0;
  for (; i + 4 <= cn; i += 4) {
    int4 r = *(const int4*)(br + i);
    float4 w = *(const float4*)(bw + i);
    float4 v0 = s4[(size_t)r.x * 32 + lane];
    float4 v1 = s4[(size_t)r.y * 32 + lane];
    float4 v2 = s4[(size_t)r.z * 32 + lane];
    float4 v3 = s4[(size_t)r.w * 32 + lane];
    a0.x = fmaf(w.x, v0.x, a0.x); a0.y = fmaf(w.x, v0.y, a0.y);
    a0.z = fmaf(w.x, v0.z, a0.z); a0.w = fmaf(w.x, v0.w, a0.w);
    a1.x = fmaf(w.y, v1.x, a1.x); a1.y = fmaf(w.y, v1.y, a1.y);
    a1.z = fmaf(w.y, v1.z, a1.z); a1.w = fmaf(w.y, v1.w, a1.w);
    a2.x = fmaf(w.z, v2.x, a2.x); a2.y = fmaf(w.z, v2.y, a2.y);
    a2.z = fmaf(w.z, v2.z, a2.z); a2.w = fmaf(w.z, v2.w, a2.w);
    a3.x = fmaf(w.w, v3.x, a3.x); a3.y = fmaf(w.w, v3.y, a3.y);
    a3.z = fmaf(w.w, v3.z, a3.z); a3.w = fmaf(w.w, v3.w, a3.w);
  }
  for (; i < cn; ++i) {
    float w = bw[i];
    float4 v = s4[(size_t)br[i] * 32 + lane];
    a0.x = fmaf(w, v.x, a0.x); a0.y = fmaf(w, v.y, a0.y);
    a0.z = fmaf(w, v.z, a0.z); a0.w = fmaf(w, v.w, a0.w);
  }
  float4 acc;
  acc.x = (a0.x + a1.x) + (a2.x + a3.x);
  acc.y = (a0.y + a1.y) + (a2.y + a3.y);
  acc.z = (a0.z + a1.z) + (a2.z + a3.z);
  acc.w = (a0.w + a1.w) + (a2.w + a3.w);

  if (PHASE == 1) {
    *(float4*)(T1 + (size_t)node * 128 + lane * 4) = acc;
    ushort4 u;
    u.x = f2bf(acc.x); u.y = f2bf(acc.y); u.z = f2bf(acc.z); u.w = f2bf(acc.w);
    *(ushort4*)(U + (size_t)node * 512 + 256 + lane * 4) = u;
  } else {
    float4 h = *(const float4*)(H + (size_t)node * 128 + lane * 4);
    float4 v;
    v.x = 2.f * acc.x - h.x; v.y = 2.f * acc.y - h.y;
    v.z = 2.f * acc.z - h.z; v.w = 2.f * acc.w - h.w;
    ushort4 u;
    u.x = f2bf(v.x); u.y = f2bf(v.y); u.z = f2bf(v.z); u.w = f2bf(v.w);
    *(ushort4*)(U + (size_t)node * 512 + 384 + lane * 4) = u;
  }
}

// ---- build B^T [512 j][512 k] bf16, col interleave j = d*4 + g; plus bias[512] ----
__global__ void k_bt(const float* __restrict__ W, const float* __restrict__ b,
                     const float* __restrict__ cW, const float* __restrict__ cb,
                     ushort_t* __restrict__ Bt, float* __restrict__ bias) {
  int idx = blockIdx.x * 256 + threadIdx.x;
  if (idx >= 512 * 512) return;
  int j = idx >> 9, k = idx & 511;
  int dd = j >> 2, g = j & 3;
  float v;
  if (k < 128) v = W[(g * 128 + k) * 128 + dd];
  else {
    int kk = k - 128;
    int blk = kk >> 7;
    v = cW[((g * 3 + blk) * 128 + (kk & 127)) * 128 + dd];
  }
  Bt[idx] = f2bf(v);
  if (k == 0) bias[j] = b[g * 128 + dd] + cb[g * 128 + dd];
}

// ---- fused GEMM (N x 512 x 512, bf16 MFMA) + LSTM epilogue ----
__global__ __launch_bounds__(256) void k_gemm(
    const ushort_t* __restrict__ U, const ushort_t* __restrict__ Bt,
    const float* __restrict__ bias, const float* __restrict__ C,
    float* __restrict__ out) {
  __shared__ float ldsF[8448];           // 33792 B: staging (32KB) then 64x132 f32 tile
  char* ldsA = (char*)ldsF;
  char* ldsB = ldsA + 16384;

  const int tid = threadIdx.x;
  const int lane = tid & 63;
  const int w = tid >> 6;
  const int wr = w >> 1, wc = w & 1;
  const int m0 = blockIdx.y * 128;
  const int n0 = blockIdx.x * 128;
  const int l15 = lane & 15;
  const int l4 = lane >> 4;

  f32x4 acc[4][4] = {};

  for (int kt = 0; kt < 8; ++kt) {
    const int k0 = kt * 64;
#pragma unroll
    for (int is = 0; is < 4; ++is) {
      int s = is * 256 + tid;
      int row = s >> 3;
      int cs = (s & 7) ^ (row & 7);        // inverse-swizzled global source chunk
      const ushort_t* ga = U + (size_t)(m0 + row) * 512 + k0 + cs * 8;
      const ushort_t* gb = Bt + (size_t)(n0 + row) * 512 + k0 + cs * 8;
      char* la = ldsA + (is * 256 + (tid & 192)) * 16;   // wave-uniform base
      char* lb = ldsB + (is * 256 + (tid & 192)) * 16;
      __builtin_amdgcn_global_load_lds((const __attribute__((address_space(1))) void*)ga,
                                       (__attribute__((address_space(3))) void*)la, 16, 0, 0);
      __builtin_amdgcn_global_load_lds((const __attribute__((address_space(1))) void*)gb,
                                       (__attribute__((address_space(3))) void*)lb, 16, 0, 0);
    }
    asm volatile("s_waitcnt vmcnt(0)" ::: "memory");
    __syncthreads();

#pragma unroll
    for (int ks = 0; ks < 2; ++ks) {
      bf16x8 af[4], bfr[4];
#pragma unroll
      for (int mi = 0; mi < 4; ++mi) {
        int ra = wr * 64 + mi * 16 + l15;
        int slot = (ks * 4 + l4) ^ (ra & 7);   // swizzled read
        af[mi] = *(const bf16x8*)(ldsA + ra * 128 + slot * 16);
      }
#pragma unroll
      for (int ni = 0; ni < 4; ++ni) {
        int rb = wc * 64 + ni * 16 + l15;
        int slot = (ks * 4 + l4) ^ (rb & 7);
        bfr[ni] = *(const bf16x8*)(ldsB + rb * 128 + slot * 16);
      }
#pragma unroll
      for (int mi = 0; mi < 4; ++mi)
#pragma unroll
        for (int ni = 0; ni < 4; ++ni)
          acc[mi][ni] = __builtin_amdgcn_mfma_f32_16x16x32_bf16(af[mi], bfr[ni], acc[mi][ni], 0, 0, 0);
    }
    __syncthreads();
  }

  // epilogue: two row-halves through LDS, then fused LSTM elementwise
#pragma unroll
  for (int half = 0; half < 2; ++half) {
    if (wr == half) {
#pragma unroll
      for (int ni = 0; ni < 4; ++ni) {
        int col = wc * 64 + ni * 16 + l15;
        float bv = bias[n0 + col];
#pragma unroll
        for (int mi = 0; mi < 4; ++mi)
#pragma unroll
          for (int r = 0; r < 4; ++r)
            ldsF[(mi * 16 + l4 * 4 + r) * 132 + col] = acc[mi][ni][r] + bv;
      }
    }
    __syncthreads();
    for (int p = tid; p < 64 * 32; p += 256) {
      int rl = p >> 5, f = p & 31;
      int n = m0 + half * 64 + rl;
      if (n < N_NODES) {
        float4 pre = *(const float4*)&ldsF[rl * 132 + f * 4];
        int dg = (n0 >> 2) + f;
        float ig = 1.f / (1.f + __expf(-pre.x));
        float fg = 1.f / (1.f + __expf(-pre.y));
        float zc = fminf(fmaxf(pre.z, -15.f), 15.f);
        float e2 = __expf(2.f * zc);
        float tg = (e2 - 1.f) / (e2 + 1.f);
        float og = 1.f / (1.f + __expf(-pre.w));
        float cOld = C[(size_t)n * 128 + dg];
        float cn = fg * cOld + ig * tg;
        float zn = fminf(fmaxf(cn, -15.f), 15.f);
        float en = __expf(2.f * zn);
        out[(size_t)n * 128 + dg] = og * (en - 1.f) / (en + 1.f);
      }
    }
    __syncthreads();
  }
}

extern "C" void kernel_launch(void* const* d_in, const int* in_sizes, int n_in,
                              void* d_out, int out_size, void* d_ws, size_t ws_size,
                              hipStream_t stream) {
  const float* X  = (const float*)d_in[0];
  const int*   ei = (const int*)d_in[1];
  const float* ew = (const float*)d_in[2];
  const float* H  = (const float*)d_in[3];
  const float* C  = (const float*)d_in[4];
  const float* W  = (const float*)d_in[5];
  const float* b  = (const float*)d_in[6];
  const float* cW = (const float*)d_in[7];
  const float* cb = (const float*)d_in[8];
  float* out = (float*)d_out;
  char* ws = (char*)d_ws;

  float*    deg  = (float*)(ws);                 // 0.4 MB
  int*      cnt  = (int*)(ws + 0x80000);         // 0.4 MB
  int*      bRow = (int*)(ws + 0x100000);        // 25.6 MB
  float*    bW   = (float*)(ws + 0x1B00000);     // 25.6 MB
  float*    T1   = (float*)(ws + 0x3500000);     // 51.2 MB
  ushort_t* U    = (ushort_t*)(ws + 0x6600000);  // (N+128)x512 bf16 = 102.5 MB
  ushort_t* Bt   = (ushort_t*)(ws + 0xC800000);  // 512 KB
  float*    bias = (float*)(ws + 0xC880000);     // 2 KB

  hipMemsetAsync(ws, 0, 0x100000, stream);       // zero deg + cnt

  k_deg<<<(N_EDGES + 255) / 256, 256, 0, stream>>>(ei, ew, deg);
  k_dinv<<<(N_NODES + 255) / 256, 256, 0, stream>>>(deg);
  k_bucket<<<(N_EDGES + 255) / 256, 256, 0, stream>>>(ei, ew, deg, cnt, bRow, bW);
  k_pack_xh<<<(N_NODES * 32 + 255) / 256, 256, 0, stream>>>(X, H, U);
  k_bt<<<1024, 256, 0, stream>>>(W, b, cW, cb, Bt, bias);
  k_gather<1><<<(N_NODES + 7) / 8, 256, 0, stream>>>(cnt, bRow, bW, H, nullptr, T1, U);
  k_gather<2><<<(N_NODES + 7) / 8, 256, 0, stream>>>(cnt, bRow, bW, T1, H, nullptr, U);
  dim3 grid(4, 782);
  k_gemm<<<grid, 256, 0, stream>>>(U, Bt, bias, C, out);
}

// Round 3
// 569.932 us; speedup vs baseline: 1.6478x; 1.0814x over previous
//
#include <hip/hip_runtime.h>

#define N_NODES 100000
#define N_EDGES 1600000
#define CAP 64

typedef unsigned short ushort_t;
typedef __attribute__((ext_vector_type(8))) short bf16x8;
typedef __attribute__((ext_vector_type(4))) float f32x4;

__device__ __forceinline__ unsigned short f2bf(float f) {
  unsigned int u = __float_as_uint(f);
  u = (u + 0x7FFFu + ((u >> 16) & 1u)) >> 16;
  return (unsigned short)u;
}

// ---- degree accumulation: deg[row] += ew ----
__global__ void k_deg(const int* __restrict__ ei, const float* __restrict__ ew,
                      float* __restrict__ deg) {
  int e = blockIdx.x * 256 + threadIdx.x;
  if (e < N_EDGES) atomicAdd(&deg[ei[e]], ew[e]);
}

// ---- bucket edges by destination col, storing packed (row, w) int2 ----
__global__ void k_bucket(const int* __restrict__ ei, const float* __restrict__ ew,
                         const float* __restrict__ deg, int* __restrict__ cnt,
                         int2* __restrict__ bE) {
  int e = blockIdx.x * 256 + threadIdx.x;
  if (e >= N_EDGES) return;
  int r = ei[e], c = ei[N_EDGES + e];
  float dr = deg[r], dc = deg[c];
  float ir = dr > 0.f ? rsqrtf(dr) : 0.f;
  float ic = dc > 0.f ? rsqrtf(dc) : 0.f;
  float wv = -ir * ew[e] * ic;
  int pos = atomicAdd(&cnt[c], 1);
  if (pos < CAP) bE[c * CAP + pos] = make_int2(r, __float_as_int(wv));
}

// ---- pack X (cols 0-127) and H (cols 128-255) into bf16 A-matrix U [N][512] ----
__global__ void k_pack_xh(const float* __restrict__ X, const float* __restrict__ H,
                          ushort_t* __restrict__ U) {
  int i = blockIdx.x * 256 + threadIdx.x;
  if (i >= N_NODES * 32) return;
  int n = i >> 5, q = i & 31;
  float4 x = *(const float4*)(X + (size_t)n * 128 + q * 4);
  float4 h = *(const float4*)(H + (size_t)n * 128 + q * 4);
  ushort4 a, bb;
  a.x = f2bf(x.x); a.y = f2bf(x.y); a.z = f2bf(x.z); a.w = f2bf(x.w);
  bb.x = f2bf(h.x); bb.y = f2bf(h.y); bb.z = f2bf(h.z); bb.w = f2bf(h.w);
  *(ushort4*)(U + (size_t)n * 512 + q * 4) = a;
  *(ushort4*)(U + (size_t)n * 512 + 128 + q * 4) = bb;
}

#define FMA4(A, W, V) \
  A.x = fmaf(W, V.x, A.x); A.y = fmaf(W, V.y, A.y); \
  A.z = fmaf(W, V.z, A.z); A.w = fmaf(W, V.w, A.w);

// ---- ILP gather: 32 lanes/node (float4 each), 8-deep unroll, 8 accumulators ----
// PHASE 1: T1 = L_hat @ H          -> T1 (f32) + U cols 256..383
// PHASE 2: T2 = 2*(L_hat @ T1) - H -> U cols 384..511
template <int PHASE>
__global__ __launch_bounds__(256) void k_gather(
    const int* __restrict__ cnt, const int2* __restrict__ bE,
    const float* __restrict__ src, const float* __restrict__ H,
    float* __restrict__ T1, ushort_t* __restrict__ U) {
  int g = threadIdx.x >> 5, lane = threadIdx.x & 31;
  int node = blockIdx.x * 8 + g;
  if (node >= N_NODES) return;
  int cn = cnt[node]; if (cn > CAP) cn = CAP;
  const int2* be = bE + node * CAP;
  const float4* s4 = (const float4*)src;

  float4 z = {0.f, 0.f, 0.f, 0.f};
  float4 a0 = z, a1 = z, a2 = z, a3 = z, a4 = z, a5 = z, a6 = z, a7 = z;
  int i = 0;
  for (; i + 8 <= cn; i += 8) {
    int4 p0 = *(const int4*)(be + i);
    int4 p1 = *(const int4*)(be + i + 2);
    int4 p2 = *(const int4*)(be + i + 4);
    int4 p3 = *(const int4*)(be + i + 6);
    float4 v0 = s4[(size_t)p0.x * 32 + lane];
    float4 v1 = s4[(size_t)p0.z * 32 + lane];
    float4 v2 = s4[(size_t)p1.x * 32 + lane];
    float4 v3 = s4[(size_t)p1.z * 32 + lane];
    float4 v4 = s4[(size_t)p2.x * 32 + lane];
    float4 v5 = s4[(size_t)p2.z * 32 + lane];
    float4 v6 = s4[(size_t)p3.x * 32 + lane];
    float4 v7 = s4[(size_t)p3.z * 32 + lane];
    FMA4(a0, __int_as_float(p0.y), v0); FMA4(a1, __int_as_float(p0.w), v1);
    FMA4(a2, __int_as_float(p1.y), v2); FMA4(a3, __int_as_float(p1.w), v3);
    FMA4(a4, __int_as_float(p2.y), v4); FMA4(a5, __int_as_float(p2.w), v5);
    FMA4(a6, __int_as_float(p3.y), v6); FMA4(a7, __int_as_float(p3.w), v7);
  }
  for (; i + 4 <= cn; i += 4) {
    int4 p0 = *(const int4*)(be + i);
    int4 p1 = *(const int4*)(be + i + 2);
    float4 v0 = s4[(size_t)p0.x * 32 + lane];
    float4 v1 = s4[(size_t)p0.z * 32 + lane];
    float4 v2 = s4[(size_t)p1.x * 32 + lane];
    float4 v3 = s4[(size_t)p1.z * 32 + lane];
    FMA4(a0, __int_as_float(p0.y), v0); FMA4(a1, __int_as_float(p0.w), v1);
    FMA4(a2, __int_as_float(p1.y), v2); FMA4(a3, __int_as_float(p1.w), v3);
  }
  for (; i < cn; ++i) {
    int2 p = be[i];
    float4 v = s4[(size_t)p.x * 32 + lane];
    FMA4(a0, __int_as_float(p.y), v);
  }
  float4 acc;
  acc.x = ((a0.x + a1.x) + (a2.x + a3.x)) + ((a4.x + a5.x) + (a6.x + a7.x));
  acc.y = ((a0.y + a1.y) + (a2.y + a3.y)) + ((a4.y + a5.y) + (a6.y + a7.y));
  acc.z = ((a0.z + a1.z) + (a2.z + a3.z)) + ((a4.z + a5.z) + (a6.z + a7.z));
  acc.w = ((a0.w + a1.w) + (a2.w + a3.w)) + ((a4.w + a5.w) + (a6.w + a7.w));

  if (PHASE == 1) {
    *(float4*)(T1 + (size_t)node * 128 + lane * 4) = acc;
    ushort4 u;
    u.x = f2bf(acc.x); u.y = f2bf(acc.y); u.z = f2bf(acc.z); u.w = f2bf(acc.w);
    *(ushort4*)(U + (size_t)node * 512 + 256 + lane * 4) = u;
  } else {
    float4 h = *(const float4*)(H + (size_t)node * 128 + lane * 4);
    float4 v;
    v.x = 2.f * acc.x - h.x; v.y = 2.f * acc.y - h.y;
    v.z = 2.f * acc.z - h.z; v.w = 2.f * acc.w - h.w;
    ushort4 u;
    u.x = f2bf(v.x); u.y = f2bf(v.y); u.z = f2bf(v.z); u.w = f2bf(v.w);
    *(ushort4*)(U + (size_t)node * 512 + 384 + lane * 4) = u;
  }
}

// ---- build B^T [512 j][512 k] bf16, col interleave j = d*4 + g; plus bias[512] ----
__global__ void k_bt(const float* __restrict__ W, const float* __restrict__ b,
                     const float* __restrict__ cW, const float* __restrict__ cb,
                     ushort_t* __restrict__ Bt, float* __restrict__ bias) {
  int idx = blockIdx.x * 256 + threadIdx.x;
  if (idx >= 512 * 512) return;
  int j = idx >> 9, k = idx & 511;
  int dd = j >> 2, g = j & 3;
  float v;
  if (k < 128) v = W[(g * 128 + k) * 128 + dd];
  else {
    int kk = k - 128;
    int blk = kk >> 7;
    v = cW[((g * 3 + blk) * 128 + (kk & 127)) * 128 + dd];
  }
  Bt[idx] = f2bf(v);
  if (k == 0) bias[j] = b[g * 128 + dd] + cb[g * 128 + dd];
}

// ---- fused GEMM (N x 512 x 512, bf16 MFMA), double-buffered 2-phase pipeline ----
__global__ __launch_bounds__(256) void k_gemm(
    const ushort_t* __restrict__ U, const ushort_t* __restrict__ Bt,
    const float* __restrict__ bias, const float* __restrict__ C,
    float* __restrict__ out) {
  __shared__ char ldsRaw[65536];     // 2 x (16K A + 16K B); epilogue reuses as f32 tile
  char* ldsA0 = ldsRaw;
  char* ldsB0 = ldsRaw + 16384;
  char* ldsA1 = ldsRaw + 32768;
  char* ldsB1 = ldsRaw + 49152;
  float* ldsF = (float*)ldsRaw;

  const int tid = threadIdx.x;
  const int lane = tid & 63;
  const int w = tid >> 6;
  const int wr = w >> 1, wc = w & 1;
  const int m0 = blockIdx.y * 128;
  const int n0 = blockIdx.x * 128;
  const int l15 = lane & 15;
  const int l4 = lane >> 4;

  auto stage = [&](int kt, char* la_base, char* lb_base) {
    const int k0 = kt * 64;
#pragma unroll
    for (int is = 0; is < 4; ++is) {
      int s = is * 256 + tid;
      int row = s >> 3;
      int cs = (s & 7) ^ (row & 7);        // inverse-swizzled global source chunk
      const ushort_t* ga = U + (size_t)(m0 + row) * 512 + k0 + cs * 8;
      const ushort_t* gb = Bt + (size_t)(n0 + row) * 512 + k0 + cs * 8;
      char* la = la_base + (is * 256 + (tid & 192)) * 16;   // wave-uniform base
      char* lb = lb_base + (is * 256 + (tid & 192)) * 16;
      __builtin_amdgcn_global_load_lds((const __attribute__((address_space(1))) void*)ga,
                                       (__attribute__((address_space(3))) void*)la, 16, 0, 0);
      __builtin_amdgcn_global_load_lds((const __attribute__((address_space(1))) void*)gb,
                                       (__attribute__((address_space(3))) void*)lb, 16, 0, 0);
    }
  };

  f32x4 acc[4][4] = {};

  stage(0, ldsA0, ldsB0);
  __syncthreads();                         // drains vmcnt(0) + lgkmcnt(0)

  for (int kt = 0; kt < 8; ++kt) {
    char* curA = (kt & 1) ? ldsA1 : ldsA0;
    char* curB = (kt & 1) ? ldsB1 : ldsB0;
    if (kt < 7) {                          // issue next-tile loads BEFORE compute
      char* nA = (kt & 1) ? ldsA0 : ldsA1;
      char* nB = (kt & 1) ? ldsB0 : ldsB1;
      stage(kt + 1, nA, nB);
    }
#pragma unroll
    for (int ks = 0; ks < 2; ++ks) {
      bf16x8 af[4], bfr[4];
#pragma unroll
      for (int mi = 0; mi < 4; ++mi) {
        int ra = wr * 64 + mi * 16 + l15;
        int slot = (ks * 4 + l4) ^ (ra & 7);   // swizzled read
        af[mi] = *(const bf16x8*)(curA + ra * 128 + slot * 16);
      }
#pragma unroll
      for (int ni = 0; ni < 4; ++ni) {
        int rb = wc * 64 + ni * 16 + l15;
        int slot = (ks * 4 + l4) ^ (rb & 7);
        bfr[ni] = *(const bf16x8*)(curB + rb * 128 + slot * 16);
      }
#pragma unroll
      for (int mi = 0; mi < 4; ++mi)
#pragma unroll
        for (int ni = 0; ni < 4; ++ni)
          acc[mi][ni] = __builtin_amdgcn_mfma_f32_16x16x32_bf16(af[mi], bfr[ni], acc[mi][ni], 0, 0, 0);
    }
    __syncthreads();                       // one barrier per K-step (drains next-stage vmcnt)
  }

  // epilogue: two row-halves through LDS, then fused LSTM elementwise
#pragma unroll
  for (int half = 0; half < 2; ++half) {
    if (wr == half) {
#pragma unroll
      for (int ni = 0; ni < 4; ++ni) {
        int col = wc * 64 + ni * 16 + l15;
        float bv = bias[n0 + col];
#pragma unroll
        for (int mi = 0; mi < 4; ++mi)
#pragma unroll
          for (int r = 0; r < 4; ++r)
            ldsF[(mi * 16 + l4 * 4 + r) * 132 + col] = acc[mi][ni][r] + bv;
      }
    }
    __syncthreads();
    for (int p = tid; p < 64 * 32; p += 256) {
      int rl = p >> 5, f = p & 31;
      int n = m0 + half * 64 + rl;
      if (n < N_NODES) {
        float4 pre = *(const float4*)&ldsF[rl * 132 + f * 4];
        int dg = (n0 >> 2) + f;
        float ig = 1.f / (1.f + __expf(-pre.x));
        float fg = 1.f / (1.f + __expf(-pre.y));
        float zc = fminf(fmaxf(pre.z, -15.f), 15.f);
        float e2 = __expf(2.f * zc);
        float tg = (e2 - 1.f) / (e2 + 1.f);
        float og = 1.f / (1.f + __expf(-pre.w));
        float cOld = C[(size_t)n * 128 + dg];
        float cn = fg * cOld + ig * tg;
        float zn = fminf(fmaxf(cn, -15.f), 15.f);
        float en = __expf(2.f * zn);
        out[(size_t)n * 128 + dg] = og * (en - 1.f) / (en + 1.f);
      }
    }
    __syncthreads();
  }
}

extern "C" void kernel_launch(void* const* d_in, const int* in_sizes, int n_in,
                              void* d_out, int out_size, void* d_ws, size_t ws_size,
                              hipStream_t stream) {
  const float* X  = (const float*)d_in[0];
  const int*   ei = (const int*)d_in[1];
  const float* ew = (const float*)d_in[2];
  const float* H  = (const float*)d_in[3];
  const float* C  = (const float*)d_in[4];
  const float* W  = (const float*)d_in[5];
  const float* b  = (const float*)d_in[6];
  const float* cW = (const float*)d_in[7];
  const float* cb = (const float*)d_in[8];
  float* out = (float*)d_out;
  char* ws = (char*)d_ws;

  float*    deg  = (float*)(ws);                 // 0.4 MB
  int*      cnt  = (int*)(ws + 0x80000);         // 0.4 MB
  int2*     bE   = (int2*)(ws + 0x100000);       // 51.2 MB packed (row, w)
  float*    T1   = (float*)(ws + 0x3400000);     // 51.2 MB
  ushort_t* U    = (ushort_t*)(ws + 0x6600000);  // (N+128)x512 bf16 = 102.5 MB
  ushort_t* Bt   = (ushort_t*)(ws + 0xC800000);  // 512 KB
  float*    bias = (float*)(ws + 0xC880000);     // 2 KB

  hipMemsetAsync(ws, 0, 0x100000, stream);       // zero deg + cnt

  k_deg<<<(N_EDGES + 255) / 256, 256, 0, stream>>>(ei, ew, deg);
  k_bucket<<<(N_EDGES + 255) / 256, 256, 0, stream>>>(ei, ew, deg, cnt, bE);
  k_pack_xh<<<(N_NODES * 32 + 255) / 256, 256, 0, stream>>>(X, H, U);
  k_bt<<<1024, 256, 0, stream>>>(W, b, cW, cb, Bt, bias);
  k_gather<1><<<(N_NODES + 7) / 8, 256, 0, stream>>>(cnt, bE, H, nullptr, T1, U);
  k_gather<2><<<(N_NODES + 7) / 8, 256, 0, stream>>>(cnt, bE, T1, H, nullptr, U);
  dim3 grid(4, 782);
  k_gemm<<<grid, 256, 0, stream>>>(U, Bt, bias, C, out);
}

// Round 5
// 540.621 us; speedup vs baseline: 1.7372x; 1.0542x over previous
//
#include <hip/hip_runtime.h>

#define N_NODES 100000
#define N_EDGES 1600000
#define CAP 64

typedef unsigned short ushort_t;
typedef __attribute__((ext_vector_type(8))) short bf16x8;
typedef __attribute__((ext_vector_type(4))) float f32x4;
typedef __attribute__((ext_vector_type(4))) int int4e;
typedef __attribute__((ext_vector_type(4))) unsigned short ushort4e;
typedef __attribute__((ext_vector_type(4))) float float4e;

__device__ __forceinline__ unsigned short f2bf(float f) {
  unsigned int u = __float_as_uint(f);
  u = (u + 0x7FFFu + ((u >> 16) & 1u)) >> 16;
  return (unsigned short)u;
}

// ---- degree accumulation: deg[row] += ew ----
__global__ void k_deg(const int* __restrict__ ei, const float* __restrict__ ew,
                      float* __restrict__ deg) {
  int e = blockIdx.x * 256 + threadIdx.x;
  if (e < N_EDGES) atomicAdd(&deg[ei[e]], ew[e]);
}

// ---- bucket edges by destination col, storing packed (row, w) int2 ----
__global__ void k_bucket(const int* __restrict__ ei, const float* __restrict__ ew,
                         const float* __restrict__ deg, int* __restrict__ cnt,
                         int2* __restrict__ bE) {
  int e = blockIdx.x * 256 + threadIdx.x;
  if (e >= N_EDGES) return;
  int r = ei[e], c = ei[N_EDGES + e];
  float dr = deg[r], dc = deg[c];
  float ir = dr > 0.f ? rsqrtf(dr) : 0.f;
  float ic = dc > 0.f ? rsqrtf(dc) : 0.f;
  float wv = -ir * ew[e] * ic;
  int pos = atomicAdd(&cnt[c], 1);
  if (pos < CAP) bE[c * CAP + pos] = make_int2(r, __float_as_int(wv));
}

// ---- pack X (cols 0-127) and H (cols 128-255) into bf16 A-matrix U [N][512] ----
__global__ void k_pack_xh(const float* __restrict__ X, const float* __restrict__ H,
                          ushort_t* __restrict__ U) {
  int i = blockIdx.x * 256 + threadIdx.x;
  if (i >= N_NODES * 32) return;
  int n = i >> 5, q = i & 31;
  float4 x = *(const float4*)(X + (size_t)n * 128 + q * 4);
  float4 h = *(const float4*)(H + (size_t)n * 128 + q * 4);
  ushort4 a, bb;
  a.x = f2bf(x.x); a.y = f2bf(x.y); a.z = f2bf(x.z); a.w = f2bf(x.w);
  bb.x = f2bf(h.x); bb.y = f2bf(h.y); bb.z = f2bf(h.z); bb.w = f2bf(h.w);
  *(ushort4*)(U + (size_t)n * 512 + q * 4) = a;
  *(ushort4*)(U + (size_t)n * 512 + 128 + q * 4) = bb;
}

#define FMA4(A, W, V) \
  A.x = fmaf(W, V.x, A.x); A.y = fmaf(W, V.y, A.y); \
  A.z = fmaf(W, V.z, A.z); A.w = fmaf(W, V.w, A.w);

// ---- ILP gather: 32 lanes/node (float4 each), 8-deep unroll, 8 accumulators ----
template <int PHASE>
__global__ __launch_bounds__(256) void k_gather(
    const int* __restrict__ cnt, const int2* __restrict__ bE,
    const float* __restrict__ src, const float* __restrict__ H,
    float* __restrict__ T1, ushort_t* __restrict__ U) {
  int g = threadIdx.x >> 5, lane = threadIdx.x & 31;
  int node = blockIdx.x * 8 + g;
  if (node >= N_NODES) return;
  int cn = cnt[node]; if (cn > CAP) cn = CAP;
  const int2* be = bE + node * CAP;
  const float4* s4 = (const float4*)src;

  float4 z = {0.f, 0.f, 0.f, 0.f};
  float4 a0 = z, a1 = z, a2 = z, a3 = z, a4 = z, a5 = z, a6 = z, a7 = z;
  int i = 0;
  for (; i + 8 <= cn; i += 8) {
    int4e p0 = __builtin_nontemporal_load((const int4e*)(be + i));
    int4e p1 = __builtin_nontemporal_load((const int4e*)(be + i + 2));
    int4e p2 = __builtin_nontemporal_load((const int4e*)(be + i + 4));
    int4e p3 = __builtin_nontemporal_load((const int4e*)(be + i + 6));
    float4 v0 = s4[(size_t)p0.x * 32 + lane];
    float4 v1 = s4[(size_t)p0.z * 32 + lane];
    float4 v2 = s4[(size_t)p1.x * 32 + lane];
    float4 v3 = s4[(size_t)p1.z * 32 + lane];
    float4 v4 = s4[(size_t)p2.x * 32 + lane];
    float4 v5 = s4[(size_t)p2.z * 32 + lane];
    float4 v6 = s4[(size_t)p3.x * 32 + lane];
    float4 v7 = s4[(size_t)p3.z * 32 + lane];
    FMA4(a0, __int_as_float(p0.y), v0); FMA4(a1, __int_as_float(p0.w), v1);
    FMA4(a2, __int_as_float(p1.y), v2); FMA4(a3, __int_as_float(p1.w), v3);
    FMA4(a4, __int_as_float(p2.y), v4); FMA4(a5, __int_as_float(p2.w), v5);
    FMA4(a6, __int_as_float(p3.y), v6); FMA4(a7, __int_as_float(p3.w), v7);
  }
  for (; i + 4 <= cn; i += 4) {
    int4e p0 = __builtin_nontemporal_load((const int4e*)(be + i));
    int4e p1 = __builtin_nontemporal_load((const int4e*)(be + i + 2));
    float4 v0 = s4[(size_t)p0.x * 32 + lane];
    float4 v1 = s4[(size_t)p0.z * 32 + lane];
    float4 v2 = s4[(size_t)p1.x * 32 + lane];
    float4 v3 = s4[(size_t)p1.z * 32 + lane];
    FMA4(a0, __int_as_float(p0.y), v0); FMA4(a1, __int_as_float(p0.w), v1);
    FMA4(a2, __int_as_float(p1.y), v2); FMA4(a3, __int_as_float(p1.w), v3);
  }
  for (; i < cn; ++i) {
    int2 p = be[i];
    float4 v = s4[(size_t)p.x * 32 + lane];
    FMA4(a0, __int_as_float(p.y), v);
  }
  float4 acc;
  acc.x = ((a0.x + a1.x) + (a2.x + a3.x)) + ((a4.x + a5.x) + (a6.x + a7.x));
  acc.y = ((a0.y + a1.y) + (a2.y + a3.y)) + ((a4.y + a5.y) + (a6.y + a7.y));
  acc.z = ((a0.z + a1.z) + (a2.z + a3.z)) + ((a4.z + a5.z) + (a6.z + a7.z));
  acc.w = ((a0.w + a1.w) + (a2.w + a3.w)) + ((a4.w + a5.w) + (a6.w + a7.w));

  if (PHASE == 1) {
    float4e af = {acc.x, acc.y, acc.z, acc.w};
    __builtin_nontemporal_store(af, (float4e*)(T1 + (size_t)node * 128 + lane * 4));
    ushort4e u = {f2bf(acc.x), f2bf(acc.y), f2bf(acc.z), f2bf(acc.w)};
    __builtin_nontemporal_store(u, (ushort4e*)(U + (size_t)node * 512 + 256 + lane * 4));
  } else {
    float4 h = *(const float4*)(H + (size_t)node * 128 + lane * 4);
    ushort4e u = {f2bf(2.f * acc.x - h.x), f2bf(2.f * acc.y - h.y),
                  f2bf(2.f * acc.z - h.z), f2bf(2.f * acc.w - h.w)};
    __builtin_nontemporal_store(u, (ushort4e*)(U + (size_t)node * 512 + 384 + lane * 4));
  }
}

// ---- build B^T [512 j][512 k] bf16, col interleave j = d*4 + g; plus bias[512] ----
__global__ void k_bt(const float* __restrict__ W, const float* __restrict__ b,
                     const float* __restrict__ cW, const float* __restrict__ cb,
                     ushort_t* __restrict__ Bt, float* __restrict__ bias) {
  int idx = blockIdx.x * 256 + threadIdx.x;
  if (idx >= 512 * 512) return;
  int j = idx >> 9, k = idx & 511;
  int dd = j >> 2, g = j & 3;
  float v;
  if (k < 128) v = W[(g * 128 + k) * 128 + dd];
  else {
    int kk = k - 128;
    int blk = kk >> 7;
    v = cW[((g * 3 + blk) * 128 + (kk & 127)) * 128 + dd];
  }
  Bt[idx] = f2bf(v);
  if (k == 0) bias[j] = b[g * 128 + dd] + cb[g * 128 + dd];
}

// ---- fused GEMM (N x 512 x 512, bf16 MFMA), counted-vmcnt depth-2 pipeline ----
__global__ __launch_bounds__(256) void k_gemm(
    const ushort_t* __restrict__ U, const ushort_t* __restrict__ Bt,
    const float* __restrict__ bias, const float* __restrict__ C,
    float* __restrict__ out) {
  __shared__ char ldsRaw[65536];     // 2 x (16K A + 16K B); epilogue reuses as f32 tile
  char* ldsA0 = ldsRaw;
  char* ldsB0 = ldsRaw + 16384;
  char* ldsA1 = ldsRaw + 32768;
  char* ldsB1 = ldsRaw + 49152;
  float* ldsF = (float*)ldsRaw;

  const int tid = threadIdx.x;
  const int lane = tid & 63;
  const int w = tid >> 6;
  const int wr = w >> 1, wc = w & 1;
  // XCD-bijective swizzle: 3128 = 8*391; 4 n-tiles of an m-panel stay in one XCD
  const int b = blockIdx.x;
  const int g = (b & 7) * 391 + (b >> 3);
  const int m0 = (g >> 2) * 128;
  const int n0 = (g & 3) * 128;
  const int l15 = lane & 15;
  const int l4 = lane >> 4;

  auto stage = [&](int kt, char* la_base, char* lb_base) {
    const int k0 = kt * 64;
#pragma unroll
    for (int is = 0; is < 4; ++is) {
      int s = is * 256 + tid;
      int row = s >> 3;
      int cs = (s & 7) ^ (row & 7);        // inverse-swizzled global source chunk
      const ushort_t* ga = U + (size_t)(m0 + row) * 512 + k0 + cs * 8;
      const ushort_t* gb = Bt + (size_t)(n0 + row) * 512 + k0 + cs * 8;
      char* la = la_base + (is * 256 + (tid & 192)) * 16;   // wave-uniform base
      char* lb = lb_base + (is * 256 + (tid & 192)) * 16;
      __builtin_amdgcn_global_load_lds((const __attribute__((address_space(1))) void*)ga,
                                       (__attribute__((address_space(3))) void*)la, 16, 0, 0);
      __builtin_amdgcn_global_load_lds((const __attribute__((address_space(1))) void*)gb,
                                       (__attribute__((address_space(3))) void*)lb, 16, 0, 0);
    }
  };

  // C prefetch (epilogue operand), coalesced, issued before staging
  const int fcol = tid & 31;
  const int rbase = tid >> 5;
  float cpre[16];
#pragma unroll
  for (int half = 0; half < 2; ++half)
#pragma unroll
    for (int k = 0; k < 8; ++k) {
      int n = m0 + half * 64 + rbase + k * 8;
      int dg = (n0 >> 2) + fcol;
      cpre[half * 8 + k] = (n < N_NODES) ? C[(size_t)n * 128 + dg] : 0.f;
    }

  // loop-invariant swizzled LDS read offsets (slot independent of mi: 16%8==0)
  int offA[2][4], offB[2][4];
#pragma unroll
  for (int ks = 0; ks < 2; ++ks) {
    int slot = ((ks * 4 + l4) ^ (l15 & 7)) * 16;
#pragma unroll
    for (int i = 0; i < 4; ++i) {
      offA[ks][i] = (wr * 64 + i * 16 + l15) * 128 + slot;
      offB[ks][i] = (wc * 64 + i * 16 + l15) * 128 + slot;
    }
  }

  f32x4 acc[4][4] = {};

  stage(0, ldsA0, ldsB0);                  // 8 loads outstanding

  for (int kt = 0; kt < 8; ++kt) {
    char* curA = (kt & 1) ? ldsA1 : ldsA0;
    char* curB = (kt & 1) ? ldsB1 : ldsB0;
    if (kt < 7) {
      stage(kt + 1, (kt & 1) ? ldsA0 : ldsA1, (kt & 1) ? ldsB0 : ldsB1);
      asm volatile("s_waitcnt vmcnt(8)" ::: "memory");  // stage(kt) landed; stage(kt+1) in flight
    } else {
      asm volatile("s_waitcnt vmcnt(0)" ::: "memory");
    }
    __builtin_amdgcn_s_barrier();          // A: cur fully staged for all threads
    __builtin_amdgcn_sched_barrier(0);
#pragma unroll
    for (int ks = 0; ks < 2; ++ks) {
      bf16x8 af[4], bfr[4];
#pragma unroll
      for (int mi = 0; mi < 4; ++mi) af[mi] = *(const bf16x8*)(curA + offA[ks][mi]);
#pragma unroll
      for (int ni = 0; ni < 4; ++ni) bfr[ni] = *(const bf16x8*)(curB + offB[ks][ni]);
#pragma unroll
      for (int mi = 0; mi < 4; ++mi)
#pragma unroll
        for (int ni = 0; ni < 4; ++ni)
          acc[mi][ni] = __builtin_amdgcn_mfma_f32_16x16x32_bf16(af[mi], bfr[ni], acc[mi][ni], 0, 0, 0);
    }
    asm volatile("s_waitcnt lgkmcnt(0)" ::: "memory");  // my LDS reads complete
    __builtin_amdgcn_sched_barrier(0);
    __builtin_amdgcn_s_barrier();          // B: all done reading cur; safe to overwrite
  }

  // epilogue: two row-halves through LDS, then fused LSTM elementwise
#pragma unroll
  for (int half = 0; half < 2; ++half) {
    if (wr == half) {
#pragma unroll
      for (int ni = 0; ni < 4; ++ni) {
        int col = wc * 64 + ni * 16 + l15;
        float bv = bias[n0 + col];
#pragma unroll
        for (int mi = 0; mi < 4; ++mi)
#pragma unroll
          for (int r = 0; r < 4; ++r)
            ldsF[(mi * 16 + l4 * 4 + r) * 132 + col] = acc[mi][ni][r] + bv;
      }
    }
    __syncthreads();
#pragma unroll
    for (int k = 0; k < 8; ++k) {
      int p = tid + k * 256;
      int rl = p >> 5, f = p & 31;
      int n = m0 + half * 64 + rl;
      if (n < N_NODES) {
        float4 pre = *(const float4*)&ldsF[rl * 132 + f * 4];
        int dg = (n0 >> 2) + f;
        float ig = __builtin_amdgcn_rcpf(1.f + __expf(-pre.x));
        float fg = __builtin_amdgcn_rcpf(1.f + __expf(-pre.y));
        float ec = __expf(-2.f * fabsf(pre.z));
        float tg = __builtin_copysignf((1.f - ec) * __builtin_amdgcn_rcpf(1.f + ec), pre.z);
        float og = __builtin_amdgcn_rcpf(1.f + __expf(-pre.w));
        float cOld = cpre[half * 8 + k];
        float cn = fg * cOld + ig * tg;
        float en = __expf(-2.f * fabsf(cn));
        float th = __builtin_copysignf((1.f - en) * __builtin_amdgcn_rcpf(1.f + en), cn);
        out[(size_t)n * 128 + dg] = og * th;
      }
    }
    __syncthreads();
  }
}

extern "C" void kernel_launch(void* const* d_in, const int* in_sizes, int n_in,
                              void* d_out, int out_size, void* d_ws, size_t ws_size,
                              hipStream_t stream) {
  const float* X  = (const float*)d_in[0];
  const int*   ei = (const int*)d_in[1];
  const float* ew = (const float*)d_in[2];
  const float* H  = (const float*)d_in[3];
  const float* C  = (const float*)d_in[4];
  const float* W  = (const float*)d_in[5];
  const float* b  = (const float*)d_in[6];
  const float* cW = (const float*)d_in[7];
  const float* cb = (const float*)d_in[8];
  float* out = (float*)d_out;
  char* ws = (char*)d_ws;

  float*    deg  = (float*)(ws);                 // 0.4 MB
  int*      cnt  = (int*)(ws + 0x80000);         // 0.4 MB
  int2*     bE   = (int2*)(ws + 0x100000);       // 51.2 MB packed (row, w)
  float*    T1   = (float*)(ws + 0x3400000);     // 51.2 MB
  ushort_t* U    = (ushort_t*)(ws + 0x6600000);  // (N+128)x512 bf16 = 102.5 MB
  ushort_t* Bt   = (ushort_t*)(ws + 0xC800000);  // 512 KB
  float*    bias = (float*)(ws + 0xC880000);     // 2 KB

  hipMemsetAsync(ws, 0, 0x100000, stream);       // zero deg + cnt

  k_deg<<<(N_EDGES + 255) / 256, 256, 0, stream>>>(ei, ew, deg);
  k_bucket<<<(N_EDGES + 255) / 256, 256, 0, stream>>>(ei, ew, deg, cnt, bE);
  k_pack_xh<<<(N_NODES * 32 + 255) / 256, 256, 0, stream>>>(X, H, U);
  k_bt<<<1024, 256, 0, stream>>>(W, b, cW, cb, Bt, bias);
  k_gather<1><<<(N_NODES + 7) / 8, 256, 0, stream>>>(cnt, bE, H, nullptr, T1, U);
  k_gather<2><<<(N_NODES + 7) / 8, 256, 0, stream>>>(cnt, bE, T1, H, nullptr, U);
  k_gemm<<<3128, 256, 0, stream>>>(U, Bt, bias, C, out);
}